// Round 2
// baseline (18746.753 us; speedup 1.0000x reference)
//
#include <hip/hip_runtime.h>
#include <hip/hip_fp16.h>
#include <cstddef>

#define Bb 64
#define Tt 512
#define INRAW 225
#define INPAD 240
#define Hh 256
#define G4 1024
#define Ee 512
#define NCODE 128
#define NCLS 250

__device__ __forceinline__ float sigf(float x) { return 1.0f / (1.0f + expf(-x)); }

// ---------------- pad copy: [M,Ks] -> [M,Kd] zero-filled ----------------
__global__ __launch_bounds__(256) void pad_copy_k(const float* __restrict__ src,
                                                  float* __restrict__ dst,
                                                  int M, int Ks, int Kd) {
  long long idx = (long long)blockIdx.x * 256 + threadIdx.x;
  if (idx >= (long long)M * Kd) return;
  int m = (int)(idx / Kd);
  int k = (int)(idx - (long long)m * Kd);
  dst[idx] = (k < Ks) ? src[(long long)m * Ks + k] : 0.0f;
}

// ---------------- pack W[1024,K] -> wp[k][j(0..255)][g(0..3)] ----------------
// wp[((k*256)+j)*4+g] = W[(g*256+j)*K + k]
__global__ __launch_bounds__(256) void pack_w_k(const float* __restrict__ W,
                                                float* __restrict__ wp, int K) {
  int idx = blockIdx.x * 256 + threadIdx.x;   // = jg*K + k
  int jg = idx / K;
  if (jg >= 1024) return;
  int k = idx - jg * K;
  int j = jg >> 2, g = jg & 3;
  wp[(((size_t)k << 8) + j) * 4 + g] = W[(size_t)(g * 256 + j) * K + k];
}

// ---------------- GEMM: C[M,N] = A[M,K] @ Bw[N,K]^T + bias[N], fp16 out -------
// requires M%128==0, N%128==0, K%16==0, rows 16B-aligned
#define BM 128
#define BN 128
#define BKk 16
__global__ __launch_bounds__(256) void gemm_nt_bias_h(const float* __restrict__ A,
                                                      const float* __restrict__ Bw,
                                                      const float* __restrict__ bias,
                                                      __half* __restrict__ C,
                                                      int M, int N, int K) {
  __shared__ __align__(16) float As[BKk][BM];
  __shared__ __align__(16) float Bs[BKk][BN];
  const int tid = threadIdx.x;
  const int bm = blockIdx.y * BM, bn = blockIdx.x * BN;
  const int ty = tid >> 4, tx = tid & 15;
  const int srow = tid >> 1;
  const int sk = (tid & 1) * 8;

  const float* Aptr = A + (size_t)(bm + srow) * K + sk;
  const float* Bptr = Bw + (size_t)(bn + srow) * K + sk;

  float4 ra0 = *(const float4*)(Aptr);
  float4 ra1 = *(const float4*)(Aptr + 4);
  float4 rb0 = *(const float4*)(Bptr);
  float4 rb1 = *(const float4*)(Bptr + 4);

  float acc[8][8];
#pragma unroll
  for (int i = 0; i < 8; ++i)
#pragma unroll
    for (int j = 0; j < 8; ++j) acc[i][j] = 0.0f;

  for (int k0 = 0; k0 < K; k0 += BKk) {
    __syncthreads();
    As[sk + 0][srow] = ra0.x; As[sk + 1][srow] = ra0.y;
    As[sk + 2][srow] = ra0.z; As[sk + 3][srow] = ra0.w;
    As[sk + 4][srow] = ra1.x; As[sk + 5][srow] = ra1.y;
    As[sk + 6][srow] = ra1.z; As[sk + 7][srow] = ra1.w;
    Bs[sk + 0][srow] = rb0.x; Bs[sk + 1][srow] = rb0.y;
    Bs[sk + 2][srow] = rb0.z; Bs[sk + 3][srow] = rb0.w;
    Bs[sk + 4][srow] = rb1.x; Bs[sk + 5][srow] = rb1.y;
    Bs[sk + 6][srow] = rb1.z; Bs[sk + 7][srow] = rb1.w;
    __syncthreads();
    if (k0 + BKk < K) {   // prefetch next tile
      ra0 = *(const float4*)(Aptr + k0 + BKk);
      ra1 = *(const float4*)(Aptr + k0 + BKk + 4);
      rb0 = *(const float4*)(Bptr + k0 + BKk);
      rb1 = *(const float4*)(Bptr + k0 + BKk + 4);
    }
#pragma unroll
    for (int kk = 0; kk < BKk; ++kk) {
      float4 aA = *(const float4*)&As[kk][ty * 8];
      float4 aB = *(const float4*)&As[kk][ty * 8 + 4];
      float4 bA = *(const float4*)&Bs[kk][tx * 8];
      float4 bB = *(const float4*)&Bs[kk][tx * 8 + 4];
      float av[8] = {aA.x, aA.y, aA.z, aA.w, aB.x, aB.y, aB.z, aB.w};
      float bv[8] = {bA.x, bA.y, bA.z, bA.w, bB.x, bB.y, bB.z, bB.w};
#pragma unroll
      for (int i = 0; i < 8; ++i)
#pragma unroll
        for (int j = 0; j < 8; ++j)
          acc[i][j] = fmaf(av[i], bv[j], acc[i][j]);
    }
  }
  float bs[8];
#pragma unroll
  for (int j = 0; j < 8; ++j) bs[j] = bias[bn + tx * 8 + j];
#pragma unroll
  for (int i = 0; i < 8; ++i) {
    __half* crow = C + (size_t)(bm + ty * 8 + i) * N + bn + tx * 8;
#pragma unroll
    for (int j = 0; j < 8; ++j) crow[j] = __float2half(acc[i][j] + bs[j]);
  }
}

// ---------------- LSTM scan: persistent, 2 rows/block, 256 threads ------------
// thread (r = tid>>7, j0 = tid&127) handles hidden indices j0, j0+128 of row r.
// pre: fp16 [row][t][1024] (i,f,g,o blocks of 256). wp: fp32 packed [k][j][4].
__global__ __launch_bounds__(256) void lstm_scan2(
    const __half* __restrict__ preF, const float* __restrict__ wpF, float* __restrict__ hF,
    const __half* __restrict__ preB, const float* __restrict__ wpB, float* __restrict__ hB,
    int nfwd) {
  const int isB = (blockIdx.x >= nfwd) ? 1 : 0;
  const __half* pre = isB ? preB : preF;
  const float4* wp4 = (const float4*)(isB ? wpB : wpF);
  float* hout = isB ? hB : hF;
  const int blk = blockIdx.x - (isB ? nfwd : 0);
  const int tid = threadIdx.x;
  const int r = tid >> 7;
  const int j0 = tid & 127;
  const int row = blk * 2 + r;

  __shared__ __align__(16) float hsh[2][256];
  hsh[r][j0] = 0.0f;
  hsh[r][j0 + 128] = 0.0f;
  float c0 = 0.0f, c1 = 0.0f;
  const __half* prerow = pre + (size_t)row * Tt * G4;
  float* hrow = hout + (size_t)row * Tt * Hh;
  __syncthreads();

  // prefetch pre for first step
  int tfirst = isB ? (Tt - 1) : 0;
  const __half* p0 = prerow + (size_t)tfirst * G4;
  float p00 = __half2float(p0[j0]);
  float p01 = __half2float(p0[256 + j0]);
  float p02 = __half2float(p0[512 + j0]);
  float p03 = __half2float(p0[768 + j0]);
  float p10 = __half2float(p0[j0 + 128]);
  float p11 = __half2float(p0[384 + j0]);
  float p12 = __half2float(p0[640 + j0]);
  float p13 = __half2float(p0[896 + j0]);

  for (int s = 0; s < Tt; ++s) {
    int t = isB ? (Tt - 1 - s) : s;
    float a00 = p00, a01 = p01, a02 = p02, a03 = p03;
    float a10 = p10, a11 = p11, a12 = p12, a13 = p13;

    // prefetch next step's pre (overlaps with k-loop)
    int sn = (s + 1 < Tt) ? (s + 1) : s;
    int tn = isB ? (Tt - 1 - sn) : sn;
    const __half* pn = prerow + (size_t)tn * G4;
    p00 = __half2float(pn[j0]);
    p01 = __half2float(pn[256 + j0]);
    p02 = __half2float(pn[512 + j0]);
    p03 = __half2float(pn[768 + j0]);
    p10 = __half2float(pn[j0 + 128]);
    p11 = __half2float(pn[384 + j0]);
    p12 = __half2float(pn[640 + j0]);
    p13 = __half2float(pn[896 + j0]);

#pragma unroll 4
    for (int k4 = 0; k4 < 64; ++k4) {
      float4 h4 = *(const float4*)&hsh[r][k4 * 4];
      float hv[4] = {h4.x, h4.y, h4.z, h4.w};
#pragma unroll
      for (int u = 0; u < 4; ++u) {
        float hk = hv[u];
        const float4 w0 = wp4[((size_t)(k4 * 4 + u) << 8) + j0];
        const float4 w1 = wp4[((size_t)(k4 * 4 + u) << 8) + j0 + 128];
        a00 = fmaf(hk, w0.x, a00); a01 = fmaf(hk, w0.y, a01);
        a02 = fmaf(hk, w0.z, a02); a03 = fmaf(hk, w0.w, a03);
        a10 = fmaf(hk, w1.x, a10); a11 = fmaf(hk, w1.y, a11);
        a12 = fmaf(hk, w1.z, a12); a13 = fmaf(hk, w1.w, a13);
      }
    }
    float i0 = sigf(a00), f0 = sigf(a01), g0 = tanhf(a02), o0 = sigf(a03);
    c0 = f0 * c0 + i0 * g0;
    float h0 = o0 * tanhf(c0);
    float i1 = sigf(a10), f1 = sigf(a11), g1 = tanhf(a12), o1 = sigf(a13);
    c1 = f1 * c1 + i1 * g1;
    float h1 = o1 * tanhf(c1);

    __syncthreads();
    hsh[r][j0] = h0;
    hsh[r][j0 + 128] = h1;
    float* hw = hrow + (size_t)t * Hh;
    hw[j0] = h0;
    hw[j0 + 128] = h1;
    __syncthreads();
  }
}

// ---------------- VQ: 4 vectors/block, 128 threads (one code per thread) ------
#define VPB 4
__global__ __launch_bounds__(128) void vq_kernel(const float* __restrict__ hf,
                                                 const float* __restrict__ hb,
                                                 const float* __restrict__ cb,
                                                 float* __restrict__ q,
                                                 float* __restrict__ dmin) {
  const int tid = threadIdx.x;
  const int v0 = blockIdx.x * VPB;
  __shared__ __align__(16) float zs[VPB][Ee];
  __shared__ float dsh[NCODE];
  __shared__ int ish[NCODE];
  __shared__ int best[VPB];

#pragma unroll
  for (int v = 0; v < VPB; ++v) {
    size_t vb = (size_t)(v0 + v);
    zs[v][tid]       = hf[vb * Hh + tid];
    zs[v][tid + 128] = hf[vb * Hh + tid + 128];
    zs[v][tid + 256] = hb[vb * Hh + tid];
    zs[v][tid + 384] = hb[vb * Hh + tid + 128];
  }
  __syncthreads();

  float dv[VPB] = {0.0f, 0.0f, 0.0f, 0.0f};
  const float4* crow = (const float4*)(cb + (size_t)tid * Ee);
#pragma unroll 2
  for (int e4 = 0; e4 < Ee / 4; ++e4) {
    float4 cc = crow[e4];
#pragma unroll
    for (int v = 0; v < VPB; ++v) {
      float4 z = *(const float4*)&zs[v][e4 * 4];
      float t0 = z.x - cc.x, t1 = z.y - cc.y, t2 = z.z - cc.z, t3 = z.w - cc.w;
      dv[v] = fmaf(t0, t0, dv[v]);
      dv[v] = fmaf(t1, t1, dv[v]);
      dv[v] = fmaf(t2, t2, dv[v]);
      dv[v] = fmaf(t3, t3, dv[v]);
    }
  }

#pragma unroll
  for (int v = 0; v < VPB; ++v) {
    __syncthreads();
    dsh[tid] = dv[v];
    ish[tid] = tid;
    __syncthreads();
    for (int off = 64; off > 0; off >>= 1) {
      if (tid < off) {
        float dn = dsh[tid + off];
        int in_ = ish[tid + off];
        if (dn < dsh[tid] || (dn == dsh[tid] && in_ < ish[tid])) {
          dsh[tid] = dn;
          ish[tid] = in_;
        }
      }
      __syncthreads();
    }
    if (tid == 0) {
      best[v] = ish[0];
      dmin[v0 + v] = dsh[0];
    }
  }
  __syncthreads();

#pragma unroll
  for (int v = 0; v < VPB; ++v) {
    const float* cbest = cb + (size_t)best[v] * Ee;
    float* qrow = q + (size_t)(v0 + v) * Ee;
#pragma unroll
    for (int u = 0; u < 4; ++u) {
      int e = tid + u * 128;
      float z = zs[v][e];
      qrow[e] = z + (cbest[e] - z);   // mimic straight-through rounding
    }
  }
}

// ---------------- vq loss reduce ----------------
__global__ __launch_bounds__(256) void vq_reduce(const float* __restrict__ dmin,
                                                 float* __restrict__ out) {
  __shared__ float sh[256];
  int tid = threadIdx.x;
  float s = 0.0f;
  for (int i = tid; i < Bb * Tt; i += 256) s += dmin[i];
  sh[tid] = s;
  __syncthreads();
  for (int off = 128; off > 0; off >>= 1) {
    if (tid < off) sh[tid] += sh[tid + off];
    __syncthreads();
  }
  if (tid == 0) out[Bb * NCLS] = sh[0] * (1.25f / ((float)(Bb * Tt) * (float)Ee));
}

// ---------------- decoder backward, single step at t=T-1 (h_prev=c_prev=0) ----
__global__ __launch_bounds__(256) void dec_bwd_last(const float* __restrict__ q,
                                                    const float* __restrict__ wpB,  // [512][256][4]
                                                    const float* __restrict__ bias,
                                                    float* __restrict__ hb_last) {
  int b = blockIdx.x, tid = threadIdx.x;
  __shared__ __align__(16) float zsl[Ee];
  const float* qrow = q + ((size_t)b * Tt + (Tt - 1)) * Ee;
  zsl[tid] = qrow[tid];
  zsl[tid + 256] = qrow[tid + 256];
  __syncthreads();
  float a0 = bias[tid], a1 = bias[256 + tid], a2 = bias[512 + tid], a3 = bias[768 + tid];
  const float4* wp4 = (const float4*)wpB;
#pragma unroll 4
  for (int k = 0; k < Ee; ++k) {
    float zk = zsl[k];
    float4 w = wp4[((size_t)k << 8) + tid];
    a0 = fmaf(zk, w.x, a0); a1 = fmaf(zk, w.y, a1);
    a2 = fmaf(zk, w.z, a2); a3 = fmaf(zk, w.w, a3);
  }
  float i = sigf(a0), f = sigf(a1), g = tanhf(a2), o = sigf(a3);
  (void)f;
  float c = i * g;
  hb_last[b * Hh + tid] = o * tanhf(c);
}

// ---------------- classifier ----------------
__global__ __launch_bounds__(256) void classifier_k(const float* __restrict__ dec_hf,
                                                    const float* __restrict__ hb_last,
                                                    const float* __restrict__ Wcls,
                                                    const float* __restrict__ bcls,
                                                    float* __restrict__ out) {
  int b = blockIdx.x, tid = threadIdx.x;
  __shared__ __align__(16) float dl[Ee];
  dl[tid] = dec_hf[((size_t)b * Tt + (Tt - 1)) * Hh + tid];
  dl[tid + 256] = hb_last[b * Hh + tid];
  __syncthreads();
  if (tid < NCLS) {
    const float4* wr = (const float4*)(Wcls + (size_t)tid * Ee);
    float acc = bcls[tid];
#pragma unroll 4
    for (int e4 = 0; e4 < Ee / 4; ++e4) {
      float4 w = wr[e4];
      float4 z = *(const float4*)&dl[e4 * 4];
      acc = fmaf(w.x, z.x, acc);
      acc = fmaf(w.y, z.y, acc);
      acc = fmaf(w.z, z.z, acc);
      acc = fmaf(w.w, z.w, acc);
    }
    out[b * NCLS + tid] = acc;
  }
}

// ---------------- launch ----------------
extern "C" void kernel_launch(void* const* d_in, const int* in_sizes, int n_in,
                              void* d_out, int out_size, void* d_ws, size_t ws_size,
                              hipStream_t stream) {
  const float* x     = (const float*)d_in[0];
  const float* eWihF = (const float*)d_in[1];
  const float* eWhhF = (const float*)d_in[2];
  const float* ebF   = (const float*)d_in[3];
  const float* eWihB = (const float*)d_in[4];
  const float* eWhhB = (const float*)d_in[5];
  const float* ebB   = (const float*)d_in[6];
  const float* cb    = (const float*)d_in[7];
  const float* dWihF = (const float*)d_in[8];
  const float* dWhhF = (const float*)d_in[9];
  const float* dbF   = (const float*)d_in[10];
  const float* dWihB = (const float*)d_in[11];
  // d_in[12] = dec_Whh_b: unused (backward decoder state at t=T-1 starts from zero)
  const float* dbB   = (const float*)d_in[13];
  const float* Wcls  = (const float*)d_in[14];
  const float* bcls  = (const float*)d_in[15];
  float* out = (float*)d_out;
  float* w = (float*)d_ws;

  const size_t MR = (size_t)Bb * Tt;                 // 32768
  const size_t SZ_PRE_H = MR * G4 / 2;               // fp16 pre buffer, in float units
  const size_t SZ_EH   = MR * Hh;                    // 8,388,608
  const size_t SZ_XPAD = MR * INPAD;                 // 7,864,320
  const size_t SZ_WPAD = (size_t)G4 * INPAD;         // 245,760
  const size_t SZ_WP   = (size_t)256 * G4;           // 262,144
  const size_t SZ_WPK  = (size_t)512 * G4;           // 524,288
  const size_t SZ_TAIL = SZ_XPAD + 2 * SZ_WPAD + 3 * SZ_WP + SZ_WPK + MR + (size_t)Bb * Hh;

  const size_t NEED_PAR = (2 * SZ_PRE_H + 2 * SZ_EH + SZ_TAIL) * 4;   // 240,189,440 B
  const bool par = ws_size >= NEED_PAR;

  __half *preFh, *preBh, *dprf;
  float *ehf, *ehb, *xpad, *wfpad, *wbpad, *wpfe, *wpbe, *wpfd, *wpkbd, *dminp, *hbl;
  float *quant, *dhf;
  size_t o = 0;
  if (par) {
    preFh = (__half*)(w + o); o += SZ_PRE_H;
    preBh = (__half*)(w + o); o += SZ_PRE_H;
    ehf = w + o; o += SZ_EH;
    ehb = w + o; o += SZ_EH;
    quant = (float*)preFh;       // over dead preF after scans
    dprf  = preBh;               // decoder pre over dead preB
    dhf   = ehf;                 // decoder h over dead ehf (post-VQ)
  } else {
    preFh = (__half*)(w + o); o += SZ_PRE_H;   // reused for preB as well
    preBh = preFh;
    ehf = w + o; o += SZ_EH;
    ehb = w + o; o += SZ_EH;
    quant = (float*)preFh;       // over dead pre (64 MB region, exact fit)
    dprf  = (__half*)ehf;        // decoder pre over dead ehf+ehb (post-VQ)
    dhf   = (float*)preFh;       // over dead quant (after dec GEMM + dec_bwd_last)
  }
  xpad  = w + o; o += SZ_XPAD;
  wfpad = w + o; o += SZ_WPAD;
  wbpad = w + o; o += SZ_WPAD;
  wpfe  = w + o; o += SZ_WP;
  wpbe  = w + o; o += SZ_WP;
  wpfd  = w + o; o += SZ_WP;
  wpkbd = w + o; o += SZ_WPK;
  dminp = w + o; o += MR;
  hbl   = w + o; o += (size_t)Bb * Hh;

  // 1. prep: pads + packs
  hipLaunchKernelGGL(pad_copy_k, dim3((MR * INPAD) / 256), dim3(256), 0, stream,
                     x, xpad, (int)MR, INRAW, INPAD);
  hipLaunchKernelGGL(pad_copy_k, dim3((G4 * INPAD) / 256), dim3(256), 0, stream,
                     eWihF, wfpad, G4, INRAW, INPAD);
  hipLaunchKernelGGL(pad_copy_k, dim3((G4 * INPAD) / 256), dim3(256), 0, stream,
                     eWihB, wbpad, G4, INRAW, INPAD);
  hipLaunchKernelGGL(pack_w_k, dim3((G4 * 256) / 256), dim3(256), 0, stream, eWhhF, wpfe, 256);
  hipLaunchKernelGGL(pack_w_k, dim3((G4 * 256) / 256), dim3(256), 0, stream, eWhhB, wpbe, 256);
  hipLaunchKernelGGL(pack_w_k, dim3((G4 * 256) / 256), dim3(256), 0, stream, dWhhF, wpfd, 256);
  hipLaunchKernelGGL(pack_w_k, dim3((G4 * 512) / 256), dim3(256), 0, stream, dWihB, wpkbd, 512);

  const dim3 gemmGrid(G4 / BN, MR / BM);
  if (par) {
    // 2. both encoder input projections, then combined scan (64 blocks)
    hipLaunchKernelGGL(gemm_nt_bias_h, gemmGrid, dim3(256), 0, stream,
                       xpad, wfpad, ebF, preFh, (int)MR, G4, INPAD);
    hipLaunchKernelGGL(gemm_nt_bias_h, gemmGrid, dim3(256), 0, stream,
                       xpad, wbpad, ebB, preBh, (int)MR, G4, INPAD);
    hipLaunchKernelGGL(lstm_scan2, dim3(64), dim3(256), 0, stream,
                       preFh, wpfe, ehf, preBh, wpbe, ehb, 32);
  } else {
    // 2'. sequential: fwd GEMM+scan, then bwd GEMM+scan (one pre buffer)
    hipLaunchKernelGGL(gemm_nt_bias_h, gemmGrid, dim3(256), 0, stream,
                       xpad, wfpad, ebF, preFh, (int)MR, G4, INPAD);
    hipLaunchKernelGGL(lstm_scan2, dim3(32), dim3(256), 0, stream,
                       preFh, wpfe, ehf, preFh, wpfe, ehf, 32);
    hipLaunchKernelGGL(gemm_nt_bias_h, gemmGrid, dim3(256), 0, stream,
                       xpad, wbpad, ebB, preFh, (int)MR, G4, INPAD);
    hipLaunchKernelGGL(lstm_scan2, dim3(32), dim3(256), 0, stream,
                       preFh, wpbe, ehb, preFh, wpbe, ehb, 0);
  }

  // 4. VQ + loss (writes quant over dead pre region)
  hipLaunchKernelGGL(vq_kernel, dim3(MR / VPB), dim3(128), 0, stream,
                     ehf, ehb, cb, quant, dminp);
  hipLaunchKernelGGL(vq_reduce, dim3(1), dim3(256), 0, stream, dminp, out);

  // 5. decoder fwd input projection (reads quant, writes dprf — disjoint)
  hipLaunchKernelGGL(gemm_nt_bias_h, gemmGrid, dim3(256), 0, stream,
                     quant, dWihF, dbF, dprf, (int)MR, G4, Ee);

  // 6. decoder bwd (only t=T-1 contributes; reads quant before dhf overwrites it)
  hipLaunchKernelGGL(dec_bwd_last, dim3(Bb), dim3(256), 0, stream, quant, wpkbd, dbB, hbl);

  // 7. decoder fwd scan
  hipLaunchKernelGGL(lstm_scan2, dim3(32), dim3(256), 0, stream,
                     dprf, wpfd, dhf, dprf, wpfd, dhf, 32);

  // 8. classifier
  hipLaunchKernelGGL(classifier_k, dim3(Bb), dim3(256), 0, stream,
                     dhf, hbl, Wcls, bcls, out);
}

// Round 3
// 8000.525 us; speedup vs baseline: 2.3432x; 2.3432x over previous
//
#include <hip/hip_runtime.h>
#include <hip/hip_fp16.h>
#include <cstddef>

#define Bb 64
#define Tt 512
#define INRAW 225
#define INPAD 240
#define Hh 256
#define G4 1024
#define Ee 512
#define NCODE 128
#define NCLS 250

typedef _Float16 f16x2 __attribute__((ext_vector_type(2)));
union F4H { float4 f; f16x2 h[4]; };
union F2H { float2 f; f16x2 h[2]; };

__device__ __forceinline__ float sigf(float x) { return 1.0f / (1.0f + expf(-x)); }

// ---------------- pad copy: [M,Ks] -> [M,Kd] zero-filled ----------------
__global__ __launch_bounds__(256) void pad_copy_k(const float* __restrict__ src,
                                                  float* __restrict__ dst,
                                                  int M, int Ks, int Kd) {
  long long idx = (long long)blockIdx.x * 256 + threadIdx.x;
  if (idx >= (long long)M * Kd) return;
  int m = (int)(idx / Kd);
  int k = (int)(idx - (long long)m * Kd);
  dst[idx] = (k < Ks) ? src[(long long)m * Ks + k] : 0.0f;
}

// ------- pack W[1024,K] -> wp[k][j(0..255)][g(0..3)] fp32 (dec_bwd only) ------
__global__ __launch_bounds__(256) void pack_w_k(const float* __restrict__ W,
                                                float* __restrict__ wp, int K) {
  int idx = blockIdx.x * 256 + threadIdx.x;   // = jg*K + k
  int jg = idx / K;
  if (jg >= 1024) return;
  int k = idx - jg * K;
  int j = jg >> 2, g = jg & 3;
  wp[(((size_t)k << 8) + j) * 4 + g] = W[(size_t)(g * 256 + j) * K + k];
}

// ------- pack Whh[1024,256] -> half2 wp[k2][j][g] = (W[2k2][j][g], W[2k2+1][j][g])
// half2 index = (k2*256 + j)*4 + g ; W[k][j][g] = Whh[(g*256+j)*256 + k]
__global__ __launch_bounds__(256) void pack_w_h(const float* __restrict__ W,
                                                f16x2* __restrict__ wp) {
  int idx = blockIdx.x * 256 + threadIdx.x;   // 131072 total
  int g = idx & 3;
  int j = (idx >> 2) & 255;
  int k2 = idx >> 10;
  const float* src = W + (size_t)(g * 256 + j) * 256 + 2 * k2;
  f16x2 v;
  v[0] = (_Float16)src[0];
  v[1] = (_Float16)src[1];
  wp[idx] = v;
}

// ---- GEMM: C[M,N] = A[M,K] @ Bw[N,K]^T + bias[N]; fp16 out, gate-interleaved:
// out column for logical n is (n&255)*4 + (n>>8)   (layout [j][gate])
#define BM 128
#define BN 128
#define BKk 16
__global__ __launch_bounds__(256) void gemm_nt_bias_h(const float* __restrict__ A,
                                                      const float* __restrict__ Bw,
                                                      const float* __restrict__ bias,
                                                      __half* __restrict__ C,
                                                      int M, int N, int K) {
  __shared__ __align__(16) float As[BKk][BM];
  __shared__ __align__(16) float Bs[BKk][BN];
  const int tid = threadIdx.x;
  const int bm = blockIdx.y * BM, bn = blockIdx.x * BN;
  const int ty = tid >> 4, tx = tid & 15;
  const int srow = tid >> 1;
  const int sk = (tid & 1) * 8;

  const float* Aptr = A + (size_t)(bm + srow) * K + sk;
  const float* Bptr = Bw + (size_t)(bn + srow) * K + sk;

  float4 ra0 = *(const float4*)(Aptr);
  float4 ra1 = *(const float4*)(Aptr + 4);
  float4 rb0 = *(const float4*)(Bptr);
  float4 rb1 = *(const float4*)(Bptr + 4);

  float acc[8][8];
#pragma unroll
  for (int i = 0; i < 8; ++i)
#pragma unroll
    for (int j = 0; j < 8; ++j) acc[i][j] = 0.0f;

  for (int k0 = 0; k0 < K; k0 += BKk) {
    __syncthreads();
    As[sk + 0][srow] = ra0.x; As[sk + 1][srow] = ra0.y;
    As[sk + 2][srow] = ra0.z; As[sk + 3][srow] = ra0.w;
    As[sk + 4][srow] = ra1.x; As[sk + 5][srow] = ra1.y;
    As[sk + 6][srow] = ra1.z; As[sk + 7][srow] = ra1.w;
    Bs[sk + 0][srow] = rb0.x; Bs[sk + 1][srow] = rb0.y;
    Bs[sk + 2][srow] = rb0.z; Bs[sk + 3][srow] = rb0.w;
    Bs[sk + 4][srow] = rb1.x; Bs[sk + 5][srow] = rb1.y;
    Bs[sk + 6][srow] = rb1.z; Bs[sk + 7][srow] = rb1.w;
    __syncthreads();
    if (k0 + BKk < K) {
      ra0 = *(const float4*)(Aptr + k0 + BKk);
      ra1 = *(const float4*)(Aptr + k0 + BKk + 4);
      rb0 = *(const float4*)(Bptr + k0 + BKk);
      rb1 = *(const float4*)(Bptr + k0 + BKk + 4);
    }
#pragma unroll
    for (int kk = 0; kk < BKk; ++kk) {
      float4 aA = *(const float4*)&As[kk][ty * 8];
      float4 aB = *(const float4*)&As[kk][ty * 8 + 4];
      float4 bA = *(const float4*)&Bs[kk][tx * 8];
      float4 bB = *(const float4*)&Bs[kk][tx * 8 + 4];
      float av[8] = {aA.x, aA.y, aA.z, aA.w, aB.x, aB.y, aB.z, aB.w};
      float bv[8] = {bA.x, bA.y, bA.z, bA.w, bB.x, bB.y, bB.z, bB.w};
#pragma unroll
      for (int i = 0; i < 8; ++i)
#pragma unroll
        for (int j = 0; j < 8; ++j)
          acc[i][j] = fmaf(av[i], bv[j], acc[i][j]);
    }
  }
  float bs[8];
#pragma unroll
  for (int j = 0; j < 8; ++j) bs[j] = bias[bn + tx * 8 + j];
  const int colbase = bn + tx * 8;
  const int g = colbase >> 8;          // gate index (run of 8 never crosses gate blk)
  const int jj = colbase & 255;
#pragma unroll
  for (int i = 0; i < 8; ++i) {
    __half* crow = C + (size_t)(bm + ty * 8 + i) * N + jj * 4 + g;
#pragma unroll
    for (int jx = 0; jx < 8; ++jx) crow[jx * 4] = __float2half(acc[i][jx] + bs[jx]);
  }
}

// ------------- LSTM scan: 1 block = 2 rows (same direction), 256 threads ------
// thread j owns hidden unit j of BOTH rows (8 accumulators, 2 c-states).
// pre: fp16 [row][t][j*4+g]. w: half2-packed [k2][j][g] read as float4 per (k2,j).
__global__ __launch_bounds__(256) void lstm_scan_r2(
    const __half* __restrict__ preF, const float4* __restrict__ wF, float* __restrict__ hF,
    const __half* __restrict__ preB, const float4* __restrict__ wB, float* __restrict__ hB,
    int nfwd) {
  const int isB = (blockIdx.x >= nfwd) ? 1 : 0;
  const __half* pre = isB ? preB : preF;
  const float4* wrow = isB ? wB : wF;
  float* hout = isB ? hB : hF;
  const int blk = blockIdx.x - (isB ? nfwd : 0);
  const int j = threadIdx.x;
  const int row0 = blk * 2, row1 = blk * 2 + 1;

  __shared__ __align__(16) __half hsh[2][256];
  hsh[0][j] = __float2half(0.0f);
  hsh[1][j] = __float2half(0.0f);
  float c0 = 0.0f, c1 = 0.0f;
  const __half* prer0 = pre + (size_t)row0 * Tt * G4 + j * 4;
  const __half* prer1 = pre + (size_t)row1 * Tt * G4 + j * 4;
  float* hr0 = hout + (size_t)row0 * Tt * Hh + j;
  float* hr1 = hout + (size_t)row1 * Tt * Hh + j;
  __syncthreads();

  const float4* hp0 = (const float4*)&hsh[0][0];   // 32 float4 = 256 halfs
  const float4* hp1 = (const float4*)&hsh[1][0];

  for (int s = 0; s < Tt; ++s) {
    const int t = isB ? (Tt - 1 - s) : s;
    F2H pu0, pu1;
    pu0.f = *(const float2*)(prer0 + (size_t)t * G4);
    pu1.f = *(const float2*)(prer1 + (size_t)t * G4);

    float a0[4] = {0.f, 0.f, 0.f, 0.f}, a1[4] = {0.f, 0.f, 0.f, 0.f};
    F4H wb[4][4];
    F4H hb0[4], hb1[4];

#define LOADC(BI, CC) do {                                              \
      _Pragma("unroll")                                                 \
      for (int u = 0; u < 4; ++u)                                       \
        wb[BI][u].f = wrow[(size_t)((CC) * 4 + u) * 256 + j];           \
      hb0[BI].f = hp0[(CC)];                                            \
      hb1[BI].f = hp1[(CC)];                                            \
    } while (0)

#define COMP(BI) do {                                                   \
      _Pragma("unroll")                                                 \
      for (int u = 0; u < 4; ++u) {                                     \
        f16x2 h0v = hb0[BI].h[u], h1v = hb1[BI].h[u];                   \
        _Pragma("unroll")                                               \
        for (int g = 0; g < 4; ++g) {                                   \
          a0[g] = __builtin_amdgcn_fdot2(h0v, wb[BI][u].h[g], a0[g], false); \
          a1[g] = __builtin_amdgcn_fdot2(h1v, wb[BI][u].h[g], a1[g], false); \
        }                                                               \
      }                                                                 \
    } while (0)

    // prologue: chunks 0..2 -> buffers 0..2   (chunk = 4 k2 = 8 k)
    LOADC(0, 0);
    LOADC(1, 1);
    LOADC(2, 2);
    for (int cb = 0; cb < 32; cb += 4) {
      LOADC(3, cb + 3);                 // cb+3 <= 31 always
      COMP(0);
      if (cb + 4 < 32) LOADC(0, cb + 4);
      COMP(1);
      if (cb + 5 < 32) LOADC(1, cb + 5);
      COMP(2);
      if (cb + 6 < 32) LOADC(2, cb + 6);
      COMP(3);
    }
#undef LOADC
#undef COMP

    __syncthreads();   // all hsh reads of this step done

    float i0 = sigf(a0[0] + (float)pu0.h[0][0]);
    float f0 = sigf(a0[1] + (float)pu0.h[0][1]);
    float g0 = tanhf(a0[2] + (float)pu0.h[1][0]);
    float o0 = sigf(a0[3] + (float)pu0.h[1][1]);
    c0 = f0 * c0 + i0 * g0;
    float h0v = o0 * tanhf(c0);

    float i1 = sigf(a1[0] + (float)pu1.h[0][0]);
    float f1 = sigf(a1[1] + (float)pu1.h[0][1]);
    float g1 = tanhf(a1[2] + (float)pu1.h[1][0]);
    float o1 = sigf(a1[3] + (float)pu1.h[1][1]);
    c1 = f1 * c1 + i1 * g1;
    float h1v = o1 * tanhf(c1);

    hsh[0][j] = __float2half(h0v);
    hsh[1][j] = __float2half(h1v);
    hr0[(size_t)t * Hh] = h0v;
    hr1[(size_t)t * Hh] = h1v;
    __syncthreads();   // hsh ready for next step
  }
}

// ---------------- VQ: 4 vectors/block, 128 threads (one code per thread) ------
#define VPB 4
__global__ __launch_bounds__(128) void vq_kernel(const float* __restrict__ hf,
                                                 const float* __restrict__ hb,
                                                 const float* __restrict__ cb,
                                                 float* __restrict__ q,
                                                 float* __restrict__ dmin) {
  const int tid = threadIdx.x;
  const int v0 = blockIdx.x * VPB;
  __shared__ __align__(16) float zs[VPB][Ee];
  __shared__ float dsh[NCODE];
  __shared__ int ish[NCODE];
  __shared__ int best[VPB];

#pragma unroll
  for (int v = 0; v < VPB; ++v) {
    size_t vb = (size_t)(v0 + v);
    zs[v][tid]       = hf[vb * Hh + tid];
    zs[v][tid + 128] = hf[vb * Hh + tid + 128];
    zs[v][tid + 256] = hb[vb * Hh + tid];
    zs[v][tid + 384] = hb[vb * Hh + tid + 128];
  }
  __syncthreads();

  float dv[VPB] = {0.0f, 0.0f, 0.0f, 0.0f};
  const float4* crow = (const float4*)(cb + (size_t)tid * Ee);
#pragma unroll 2
  for (int e4 = 0; e4 < Ee / 4; ++e4) {
    float4 cc = crow[e4];
#pragma unroll
    for (int v = 0; v < VPB; ++v) {
      float4 z = *(const float4*)&zs[v][e4 * 4];
      float t0 = z.x - cc.x, t1 = z.y - cc.y, t2 = z.z - cc.z, t3 = z.w - cc.w;
      dv[v] = fmaf(t0, t0, dv[v]);
      dv[v] = fmaf(t1, t1, dv[v]);
      dv[v] = fmaf(t2, t2, dv[v]);
      dv[v] = fmaf(t3, t3, dv[v]);
    }
  }

#pragma unroll
  for (int v = 0; v < VPB; ++v) {
    __syncthreads();
    dsh[tid] = dv[v];
    ish[tid] = tid;
    __syncthreads();
    for (int off = 64; off > 0; off >>= 1) {
      if (tid < off) {
        float dn = dsh[tid + off];
        int in_ = ish[tid + off];
        if (dn < dsh[tid] || (dn == dsh[tid] && in_ < ish[tid])) {
          dsh[tid] = dn;
          ish[tid] = in_;
        }
      }
      __syncthreads();
    }
    if (tid == 0) {
      best[v] = ish[0];
      dmin[v0 + v] = dsh[0];
    }
  }
  __syncthreads();

#pragma unroll
  for (int v = 0; v < VPB; ++v) {
    const float* cbest = cb + (size_t)best[v] * Ee;
    float* qrow = q + (size_t)(v0 + v) * Ee;
#pragma unroll
    for (int u = 0; u < 4; ++u) {
      int e = tid + u * 128;
      float z = zs[v][e];
      qrow[e] = z + (cbest[e] - z);
    }
  }
}

// ---------------- vq loss reduce ----------------
__global__ __launch_bounds__(256) void vq_reduce(const float* __restrict__ dmin,
                                                 float* __restrict__ out) {
  __shared__ float sh[256];
  int tid = threadIdx.x;
  float s = 0.0f;
  for (int i = tid; i < Bb * Tt; i += 256) s += dmin[i];
  sh[tid] = s;
  __syncthreads();
  for (int off = 128; off > 0; off >>= 1) {
    if (tid < off) sh[tid] += sh[tid + off];
    __syncthreads();
  }
  if (tid == 0) out[Bb * NCLS] = sh[0] * (1.25f / ((float)(Bb * Tt) * (float)Ee));
}

// ---------------- decoder backward, single step at t=T-1 (h_prev=c_prev=0) ----
__global__ __launch_bounds__(256) void dec_bwd_last(const float* __restrict__ q,
                                                    const float* __restrict__ wpB,  // [512][256][4]
                                                    const float* __restrict__ bias,
                                                    float* __restrict__ hb_last) {
  int b = blockIdx.x, tid = threadIdx.x;
  __shared__ __align__(16) float zsl[Ee];
  const float* qrow = q + ((size_t)b * Tt + (Tt - 1)) * Ee;
  zsl[tid] = qrow[tid];
  zsl[tid + 256] = qrow[tid + 256];
  __syncthreads();
  float a0 = bias[tid], a1 = bias[256 + tid], a2 = bias[512 + tid], a3 = bias[768 + tid];
  const float4* wp4 = (const float4*)wpB;
#pragma unroll 4
  for (int k = 0; k < Ee; ++k) {
    float zk = zsl[k];
    float4 w = wp4[((size_t)k << 8) + tid];
    a0 = fmaf(zk, w.x, a0); a1 = fmaf(zk, w.y, a1);
    a2 = fmaf(zk, w.z, a2); a3 = fmaf(zk, w.w, a3);
  }
  float i = sigf(a0), f = sigf(a1), g = tanhf(a2), o = sigf(a3);
  (void)f;
  float c = i * g;
  hb_last[b * Hh + tid] = o * tanhf(c);
}

// ---------------- classifier ----------------
__global__ __launch_bounds__(256) void classifier_k(const float* __restrict__ dec_hf,
                                                    const float* __restrict__ hb_last,
                                                    const float* __restrict__ Wcls,
                                                    const float* __restrict__ bcls,
                                                    float* __restrict__ out) {
  int b = blockIdx.x, tid = threadIdx.x;
  __shared__ __align__(16) float dl[Ee];
  dl[tid] = dec_hf[((size_t)b * Tt + (Tt - 1)) * Hh + tid];
  dl[tid + 256] = hb_last[b * Hh + tid];
  __syncthreads();
  if (tid < NCLS) {
    const float4* wr = (const float4*)(Wcls + (size_t)tid * Ee);
    float acc = bcls[tid];
#pragma unroll 4
    for (int e4 = 0; e4 < Ee / 4; ++e4) {
      float4 w = wr[e4];
      float4 z = *(const float4*)&dl[e4 * 4];
      acc = fmaf(w.x, z.x, acc);
      acc = fmaf(w.y, z.y, acc);
      acc = fmaf(w.z, z.z, acc);
      acc = fmaf(w.w, z.w, acc);
    }
    out[b * NCLS + tid] = acc;
  }
}

// ---------------- launch ----------------
extern "C" void kernel_launch(void* const* d_in, const int* in_sizes, int n_in,
                              void* d_out, int out_size, void* d_ws, size_t ws_size,
                              hipStream_t stream) {
  const float* x     = (const float*)d_in[0];
  const float* eWihF = (const float*)d_in[1];
  const float* eWhhF = (const float*)d_in[2];
  const float* ebF   = (const float*)d_in[3];
  const float* eWihB = (const float*)d_in[4];
  const float* eWhhB = (const float*)d_in[5];
  const float* ebB   = (const float*)d_in[6];
  const float* cb    = (const float*)d_in[7];
  const float* dWihF = (const float*)d_in[8];
  const float* dWhhF = (const float*)d_in[9];
  const float* dbF   = (const float*)d_in[10];
  const float* dWihB = (const float*)d_in[11];
  // d_in[12] = dec_Whh_b: unused (backward decoder state at t=T-1 starts from zero)
  const float* dbB   = (const float*)d_in[13];
  const float* Wcls  = (const float*)d_in[14];
  const float* bcls  = (const float*)d_in[15];
  float* out = (float*)d_out;
  float* w = (float*)d_ws;

  const size_t MR = (size_t)Bb * Tt;                 // 32768
  const size_t SZ_PRE_H = MR * G4 / 2;               // fp16 pre buffer, float units
  const size_t SZ_EH   = MR * Hh;
  const size_t SZ_XPAD = MR * INPAD;
  const size_t SZ_WPAD = (size_t)G4 * INPAD;
  const size_t SZ_WPK  = (size_t)512 * G4;           // dec_bwd fp32 pack
  const size_t SZ_WPH  = (size_t)128 * 256 * 4;      // 131072 half2 = float units
  const size_t SZ_TAIL = SZ_XPAD + 2 * SZ_WPAD + SZ_WPK + 3 * SZ_WPH + MR + (size_t)Bb * Hh;

  const size_t NEED_PAR = (2 * SZ_PRE_H + 2 * SZ_EH + SZ_TAIL) * 4;
  const bool par = ws_size >= NEED_PAR;

  __half *preFh, *preBh, *dprf;
  float *ehf, *ehb, *xpad, *wfpad, *wbpad, *wpkbd, *dminp, *hbl;
  f16x2 *wphF, *wphB, *wphD;
  float *quant, *dhf;
  size_t o = 0;
  if (par) {
    preFh = (__half*)(w + o); o += SZ_PRE_H;
    preBh = (__half*)(w + o); o += SZ_PRE_H;
    ehf = w + o; o += SZ_EH;
    ehb = w + o; o += SZ_EH;
    quant = (float*)preFh;       // over dead preF after scans (64 MB, exact fit)
    dprf  = preBh;               // decoder pre over dead preB
    dhf   = ehf;                 // decoder h over dead ehf (post-VQ)
  } else {
    preFh = (__half*)(w + o); o += SZ_PRE_H;   // reused for preB as well
    preBh = preFh;
    ehf = w + o; o += SZ_EH;
    ehb = w + o; o += SZ_EH;
    quant = (float*)preFh;
    dprf  = (__half*)ehf;        // decoder pre over dead ehf+ehb (post-VQ)
    dhf   = (float*)preFh;       // over dead quant (after dec GEMM + dec_bwd_last)
  }
  xpad  = w + o; o += SZ_XPAD;
  wfpad = w + o; o += SZ_WPAD;
  wbpad = w + o; o += SZ_WPAD;
  wpkbd = w + o; o += SZ_WPK;
  wphF  = (f16x2*)(w + o); o += SZ_WPH;
  wphB  = (f16x2*)(w + o); o += SZ_WPH;
  wphD  = (f16x2*)(w + o); o += SZ_WPH;
  dminp = w + o; o += MR;
  hbl   = w + o; o += (size_t)Bb * Hh;

  // 1. prep: pads + packs
  hipLaunchKernelGGL(pad_copy_k, dim3((MR * INPAD) / 256), dim3(256), 0, stream,
                     x, xpad, (int)MR, INRAW, INPAD);
  hipLaunchKernelGGL(pad_copy_k, dim3((G4 * INPAD) / 256), dim3(256), 0, stream,
                     eWihF, wfpad, G4, INRAW, INPAD);
  hipLaunchKernelGGL(pad_copy_k, dim3((G4 * INPAD) / 256), dim3(256), 0, stream,
                     eWihB, wbpad, G4, INRAW, INPAD);
  hipLaunchKernelGGL(pack_w_k, dim3((G4 * 512) / 256), dim3(256), 0, stream, dWihB, wpkbd, 512);
  hipLaunchKernelGGL(pack_w_h, dim3(512), dim3(256), 0, stream, eWhhF, wphF);
  hipLaunchKernelGGL(pack_w_h, dim3(512), dim3(256), 0, stream, eWhhB, wphB);
  hipLaunchKernelGGL(pack_w_h, dim3(512), dim3(256), 0, stream, dWhhF, wphD);

  const dim3 gemmGrid(G4 / BN, MR / BM);
  if (par) {
    hipLaunchKernelGGL(gemm_nt_bias_h, gemmGrid, dim3(256), 0, stream,
                       xpad, wfpad, ebF, preFh, (int)MR, G4, INPAD);
    hipLaunchKernelGGL(gemm_nt_bias_h, gemmGrid, dim3(256), 0, stream,
                       xpad, wbpad, ebB, preBh, (int)MR, G4, INPAD);
    hipLaunchKernelGGL(lstm_scan_r2, dim3(64), dim3(256), 0, stream,
                       preFh, (const float4*)wphF, ehf,
                       preBh, (const float4*)wphB, ehb, 32);
  } else {
    hipLaunchKernelGGL(gemm_nt_bias_h, gemmGrid, dim3(256), 0, stream,
                       xpad, wfpad, ebF, preFh, (int)MR, G4, INPAD);
    hipLaunchKernelGGL(lstm_scan_r2, dim3(32), dim3(256), 0, stream,
                       preFh, (const float4*)wphF, ehf,
                       preFh, (const float4*)wphF, ehf, 32);
    hipLaunchKernelGGL(gemm_nt_bias_h, gemmGrid, dim3(256), 0, stream,
                       xpad, wbpad, ebB, preFh, (int)MR, G4, INPAD);
    hipLaunchKernelGGL(lstm_scan_r2, dim3(32), dim3(256), 0, stream,
                       preFh, (const float4*)wphB, ehb,
                       preFh, (const float4*)wphB, ehb, 0);
  }

  // 4. VQ + loss
  hipLaunchKernelGGL(vq_kernel, dim3(MR / VPB), dim3(128), 0, stream,
                     ehf, ehb, cb, quant, dminp);
  hipLaunchKernelGGL(vq_reduce, dim3(1), dim3(256), 0, stream, dminp, out);

  // 5. decoder fwd input projection
  hipLaunchKernelGGL(gemm_nt_bias_h, gemmGrid, dim3(256), 0, stream,
                     quant, dWihF, dbF, dprf, (int)MR, G4, Ee);

  // 6. decoder bwd (only t=T-1 contributes; reads quant before dhf overwrites)
  hipLaunchKernelGGL(dec_bwd_last, dim3(Bb), dim3(256), 0, stream, quant, wpkbd, dbB, hbl);

  // 7. decoder fwd scan
  hipLaunchKernelGGL(lstm_scan_r2, dim3(32), dim3(256), 0, stream,
                     dprf, (const float4*)wphD, dhf,
                     dprf, (const float4*)wphD, dhf, 32);

  // 8. classifier
  hipLaunchKernelGGL(classifier_k, dim3(Bb), dim3(256), 0, stream,
                     dhf, hbl, Wcls, bcls, out);
}